// Round 3
// baseline (302.548 us; speedup 1.0000x reference)
//
#include <hip/hip_runtime.h>
#include <hip/hip_bf16.h>

// Problem constants
#define T_IN   16384
#define T_OUT  16376
#define CIN    64
#define NF     64
#define KT     9
#define NB     32
#define TILE   128                 // output rows per tile
#define ROWS   (TILE + KT - 1)     // 136 staged input rows
#define LDS_STRIDE 72              // shorts per row: 64 + 8 pad (144 B, breaks 128B stride)
#define NBLOCKS 512
#define TILE_ITERS 8               // 512 blocks * 8 tiles = 4096 = 32 batches * 128 tiles
#define CHUNKS (ROWS * 16)         // 2176 float4 chunks per tile; 256 thr * 9 = 2304 slots

typedef __bf16 bf16x8 __attribute__((ext_vector_type(8)));
typedef unsigned short u16x8 __attribute__((ext_vector_type(8)));
typedef unsigned short u16x4 __attribute__((ext_vector_type(4)));
typedef float f32x16 __attribute__((ext_vector_type(16)));

// fp32 -> bf16 round-to-nearest-even (bit twiddle)
__device__ __forceinline__ unsigned short f2bf(float f) {
    unsigned u = __builtin_bit_cast(unsigned, f);
    u += 0x7FFFu + ((u >> 16) & 1u);
    return (unsigned short)(u >> 16);
}

__global__ __launch_bounds__(256, 2) void conv1d_mfma_kernel(
    const float* __restrict__ x,   // [32][16384][64]
    const float* __restrict__ w,   // [64][9][64]
    const float* __restrict__ b,   // [64]
    float* __restrict__ out)       // [32][16376][64]
{
    // Double-buffered bf16 input tile (39168 B total)
    __shared__ __attribute__((aligned(16))) unsigned short ldsX[2][ROWS * LDS_STRIDE];

    const int tid  = threadIdx.x;
    const int lane = tid & 63;
    const int wv   = tid >> 6;        // 4 waves
    const int half = lane >> 5;       // 0/1: k-half of MFMA operand
    const int l31  = lane & 31;
    const int fh   = wv & 1;          // filter half (0: f 0..31, 1: f 32..63)
    const int rh   = wv >> 1;         // row half (0: rows 0..63, 1: rows 64..127)
    const int rbase = rh * 64;
    const int fcol  = fh * 32 + l31;  // this lane's output filter column

    // ---- Load all weight B-fragments into registers (once per block) ----
    // B[k_inner][n] layout for mfma_f32_32x32x16_bf16: n = lane&31, k_inner = (lane>>5)*8 + j
    bf16x8 Bf[KT][4];
#pragma unroll
    for (int k = 0; k < KT; ++k) {
#pragma unroll
        for (int s = 0; s < 4; ++s) {
            const float* wp = w + (size_t)fcol * (KT * CIN) + k * CIN + s * 16 + half * 8;
            const float4 w0 = *(const float4*)(wp);
            const float4 w1 = *(const float4*)(wp + 4);
            u16x8 t;
            t[0] = f2bf(w0.x); t[1] = f2bf(w0.y); t[2] = f2bf(w0.z); t[3] = f2bf(w0.w);
            t[4] = f2bf(w1.x); t[5] = f2bf(w1.y); t[6] = f2bf(w1.z); t[7] = f2bf(w1.w);
            Bf[k][s] = __builtin_bit_cast(bf16x8, t);
        }
    }
    const float bias = b[fcol];

    // Per-thread chunk decomposition: chunk k covers float4 idx = k*256 + tid
    // (k==8 only valid for tid<128). r = idx>>4 (row), cg = idx&15 (16B group).
    const int base = blockIdx.x * TILE_ITERS;

    auto load_chunk = [&](int g, int k) -> float4 {
        const int idx = k * 256 + tid;
        const int r   = idx >> 4;
        const int cg  = idx & 15;
        const int bb2 = g >> 7;
        int gr = ((g & 127) << 7) + r;
        gr = gr < (T_IN - 1) ? gr : (T_IN - 1);   // clamp (last tile of batch; discarded)
        return *(const float4*)(x + ((size_t)bb2 * T_IN + gr) * CIN + cg * 4);
    };

    float4 st[KT];   // 9 staged chunks, all indices compile-time (registers)

    // ---- Prologue: load+consume tile base into buf0; preload tile base+1 ----
#pragma unroll
    for (int k = 0; k < KT; ++k)
        if (k < 8 || tid < 128) st[k] = load_chunk(base, k);
#pragma unroll
    for (int k = 0; k < KT; ++k) {
        if (k < 8 || tid < 128) {
            const int idx = k * 256 + tid;
            const int r = idx >> 4, cg = idx & 15;
            u16x4 p;
            p[0] = f2bf(st[k].x); p[1] = f2bf(st[k].y);
            p[2] = f2bf(st[k].z); p[3] = f2bf(st[k].w);
            *(u16x4*)&ldsX[0][r * LDS_STRIDE + cg * 4] = p;
        }
    }
#pragma unroll
    for (int k = 0; k < KT; ++k)
        if (k < 8 || tid < 128) st[k] = load_chunk(base + 1, k);
    __syncthreads();

    for (int it = 0; it < TILE_ITERS; ++it) {
        const int g  = base + it;
        const int bb = g >> 7;
        const int t0 = (g & 127) << 7;
        const int c  = it & 1;
        const unsigned short* lx = ldsX[c];        // compute buffer (tile g)
        unsigned short*       lw = ldsX[c ^ 1];    // staging target (tile g+1)
        const bool cons = (it < TILE_ITERS - 1);   // consume st -> lw (tile g+1)
        const bool lood = (it < TILE_ITERS - 2);   // reload st <- tile g+2

        // ---- MFMA main loop with interleaved consume/reload (progressive staging) ----
        f32x16 acc0 = {0,0,0,0,0,0,0,0,0,0,0,0,0,0,0,0};
        f32x16 acc1 = {0,0,0,0,0,0,0,0,0,0,0,0,0,0,0,0};
        const int abase = (rbase + l31) * LDS_STRIDE + half * 8;
#pragma unroll
        for (int k = 0; k < KT; ++k) {
#pragma unroll
            for (int s = 0; s < 4; ++s) {
                const int off = abase + k * LDS_STRIDE + s * 16;
                bf16x8 a0 = *(const bf16x8*)&lx[off];
                bf16x8 a1 = *(const bf16x8*)&lx[off + 32 * LDS_STRIDE];
                acc0 = __builtin_amdgcn_mfma_f32_32x32x16_bf16(a0, Bf[k][s], acc0, 0, 0, 0);
                acc1 = __builtin_amdgcn_mfma_f32_32x32x16_bf16(a1, Bf[k][s], acc1, 0, 0, 0);
            }
            // consume chunk k of tile g+1 (loaded last iteration -> no latency stall)
            if (cons && (k < 8 || tid < 128)) {
                const int idx = k * 256 + tid;
                const int r = idx >> 4, cg = idx & 15;
                u16x4 p;
                p[0] = f2bf(st[k].x); p[1] = f2bf(st[k].y);
                p[2] = f2bf(st[k].z); p[3] = f2bf(st[k].w);
                *(u16x4*)&lw[r * LDS_STRIDE + cg * 4] = p;
            }
            // reload chunk k for tile g+2 (consumed next iteration)
            if (lood && (k < 8 || tid < 128)) {
                st[k] = load_chunk(g + 2, k);
            }
        }

        // ---- Epilogue BEFORE barrier: acc dies here (bounded register liveness) ----
        // C/D layout col=lane&31, row=(reg&3)+8*(reg>>2)+4*(lane>>5)
#pragma unroll
        for (int m = 0; m < 2; ++m) {
            const f32x16 A = m ? acc1 : acc0;
#pragma unroll
            for (int r = 0; r < 16; ++r) {
                const int tl = rbase + m * 32 + (r & 3) + 8 * (r >> 2) + 4 * half;
                const int tg = t0 + tl;
                if (tg < T_OUT)
                    out[((size_t)bb * T_OUT + tg) * NF + fcol] = A[r] + bias;
            }
        }

        __syncthreads();   // single barrier: orders staging writes of buf c^1 vs next
                           // iteration's MFMA reads, and MFMA reads of buf c vs next
                           // iteration's staging writes to it
    }
}

extern "C" void kernel_launch(void* const* d_in, const int* in_sizes, int n_in,
                              void* d_out, int out_size, void* d_ws, size_t ws_size,
                              hipStream_t stream) {
    const float* x = (const float*)d_in[0];
    const float* w = (const float*)d_in[1];
    const float* b = (const float*)d_in[2];
    float* out = (float*)d_out;
    conv1d_mfma_kernel<<<NBLOCKS, 256, 0, stream>>>(x, w, b, out);
}